// Round 1
// baseline (310.924 us; speedup 1.0000x reference)
//
#include <hip/hip_runtime.h>
#include <stdint.h>

#define NIMG 16
#define NANCH 131072
#define NCLS 10
#define ROWW 17
#define TOPK 100
#define LISTA_CAP 128
#define EQCAP 512

// ws layout in uint32 units
static const size_t HIST_OFF   = 0;       // 16*256
static const size_t PREFIX_OFF = 4096;    // 16
static const size_t TAKEN_OFF  = 4112;    // 16
static const size_t CNTA_OFF   = 4128;    // 16
static const size_t CNTB_OFF   = 4144;    // 16
static const size_t LAK_OFF    = 4160;    // 16*128 keys of >thr list
static const size_t LAI_OFF    = 6208;    // 16*128 idx
static const size_t LB_OFF     = 8256;    // 16*512 idx of ==thr list
static const size_t KEYS_OFF   = 32768;   // 16*131072 keys

__device__ __forceinline__ uint32_t fkey(float f) {
    uint32_t u = __float_as_uint(f);
    return (u & 0x80000000u) ? ~u : (u | 0x80000000u);
}

__device__ __forceinline__ float sigmoidf(float x) {
    return 1.0f / (1.0f + expf(-x));
}

// Kernel 1: per-anchor key = monotone(sigmoid(max logit)); store keys; hist of top byte.
__global__ void k_keys_hist(const float* __restrict__ pred, uint32_t* __restrict__ ws) {
    __shared__ uint32_t hs[256];
    const int img = blockIdx.y;
    const int t = threadIdx.x;
    hs[t] = 0;
    __syncthreads();
    uint32_t* keys = ws + KEYS_OFF + (size_t)img * NANCH;
    const float* base = pred + (size_t)img * NANCH * ROWW;
    const int a0 = blockIdx.x * 4096;
    for (int k = 0; k < 16; ++k) {
        const int a = a0 + t + k * 256;
        const float* row = base + (size_t)a * ROWW;
        float m = row[0];
        #pragma unroll
        for (int c = 1; c < NCLS; ++c) m = fmaxf(m, row[c]);
        const uint32_t key = fkey(sigmoidf(m));
        keys[a] = key;
        atomicAdd(&hs[key >> 24], 1u);
    }
    __syncthreads();
    atomicAdd(&ws[HIST_OFF + img * 256 + t], hs[t]);
}

// Histogram of next byte restricted to current prefix.
__global__ void k_hist(uint32_t* __restrict__ ws, int shift) {
    __shared__ uint32_t hs[256];
    const int img = blockIdx.y;
    const int t = threadIdx.x;
    hs[t] = 0;
    __syncthreads();
    const uint32_t prefix = ws[PREFIX_OFF + img];
    const uint32_t* keys = ws + KEYS_OFF + (size_t)img * NANCH;
    const int a0 = blockIdx.x * 4096;
    for (int k = 0; k < 16; ++k) {
        const uint32_t key = keys[a0 + t + k * 256];
        if ((key >> (shift + 8)) == prefix)
            atomicAdd(&hs[(key >> shift) & 255u], 1u);
    }
    __syncthreads();
    atomicAdd(&ws[HIST_OFF + img * 256 + t], hs[t]);
}

// Pick the bin containing the (100 - taken)-th largest; extend prefix; zero hist.
__global__ void k_refine(uint32_t* __restrict__ ws) {
    const int img = blockIdx.x;
    const int t = threadIdx.x;
    if (t == 0) {
        const uint32_t taken = ws[TAKEN_OFF + img];
        const uint32_t need = TOPK - taken;
        const uint32_t* h = ws + HIST_OFF + img * 256;
        uint32_t s = 0;
        int b = 255;
        for (; b >= 0; --b) {
            const uint32_t c = h[b];
            if (s + c >= need) break;
            s += c;
        }
        ws[PREFIX_OFF + img] = (ws[PREFIX_OFF + img] << 8) | (uint32_t)b;
        ws[TAKEN_OFF + img] = taken + s;
    }
    __syncthreads();
    ws[HIST_OFF + img * 256 + t] = 0;
}

// Collect candidates: key > thr into list A; key == thr into list B.
__global__ void k_collect(uint32_t* __restrict__ ws) {
    const int img = blockIdx.y;
    const int t = threadIdx.x;
    const uint32_t thr = ws[PREFIX_OFF + img];
    const uint32_t* keys = ws + KEYS_OFF + (size_t)img * NANCH;
    const int a0 = blockIdx.x * 4096;
    for (int k = 0; k < 16; ++k) {
        const int a = a0 + t + k * 256;
        const uint32_t key = keys[a];
        if (key > thr) {
            const uint32_t p = atomicAdd(&ws[CNTA_OFF + img], 1u);
            if (p < LISTA_CAP) {
                ws[LAK_OFF + (size_t)img * LISTA_CAP + p] = key;
                ws[LAI_OFF + (size_t)img * LISTA_CAP + p] = (uint32_t)a;
            }
        } else if (key == thr) {
            const uint32_t p = atomicAdd(&ws[CNTB_OFF + img], 1u);
            if (p < EQCAP) ws[LB_OFF + (size_t)img * EQCAP + p] = (uint32_t)a;
        }
    }
}

// Per-image finale: assemble top-100, order, NMS, output sort, write.
__global__ void k_final(const float* __restrict__ pred, const uint32_t* __restrict__ ws,
                        float* __restrict__ out) {
    const int img = blockIdx.x;
    const int t = threadIdx.x;
    __shared__ uint32_t skey[TOPK], sidx[TOPK], oidx[TOPK];
    __shared__ float bx[TOPK][7], ssc[TOPK];
    __shared__ int scls[TOPK], sup[TOPK];
    __shared__ float X1[TOPK], Y1[TOPK], X2[TOPK], Y2[TOPK], AR[TOPK];
    __shared__ float k2[TOPK];

    int na = (int)ws[CNTA_OFF + img];
    if (na > TOPK) na = TOPK;
    const int ne = TOPK - na;
    int nb = (int)ws[CNTB_OFF + img];
    if (nb > EQCAP) nb = EQCAP;
    const uint32_t thr = ws[PREFIX_OFF + img];
    const uint32_t* lak = ws + LAK_OFF + (size_t)img * LISTA_CAP;
    const uint32_t* lai = ws + LAI_OFF + (size_t)img * LISTA_CAP;
    const uint32_t* lb  = ws + LB_OFF  + (size_t)img * EQCAP;

    for (int q = t; q < na; q += 128) { skey[q] = lak[q]; sidx[q] = lai[q]; }
    // ties at threshold: take smallest anchor indices (top_k tie rule)
    for (int e = t; e < nb; e += 128) {
        const uint32_t idx = lb[e];
        int r = 0;
        for (int j = 0; j < nb; ++j) r += (lb[j] < idx);
        if (r < ne) { skey[na + r] = thr; sidx[na + r] = idx; }
    }
    __syncthreads();

    // order by (key desc, anchor idx asc) == top_k order (sc already sorted; argsort stable)
    for (int q = t; q < TOPK; q += 128) {
        const uint32_t k = skey[q], a = sidx[q];
        int r = 0;
        for (int j = 0; j < TOPK; ++j) {
            const uint32_t kj = skey[j], aj = sidx[j];
            r += (kj > k) || (kj == k && aj < a);
        }
        oidx[r] = a;
    }
    __syncthreads();

    // gather rows, per-class sigmoid argmax/max (first-index ties), box geometry
    for (int q = t; q < TOPK; q += 128) {
        const float* row = pred + ((size_t)img * NANCH + oidx[q]) * ROWW;
        float best = sigmoidf(row[0]);
        int am = 0;
        #pragma unroll
        for (int c = 1; c < NCLS; ++c) {
            const float s = sigmoidf(row[c]);
            if (s > best) { best = s; am = c; }
        }
        ssc[q] = best; scls[q] = am;
        const float b0 = row[10], b1 = row[11], b2v = row[12], b3 = row[13],
                    b4 = row[14], b5 = row[15], b6 = row[16];
        bx[q][0] = b0; bx[q][1] = b1; bx[q][2] = b2v; bx[q][3] = b3;
        bx[q][4] = b4; bx[q][5] = b5; bx[q][6] = b6;
        const float x1 = b0 - b3 * 0.5f, y1 = b1 - b4 * 0.5f;
        const float x2 = b0 + b3 * 0.5f, y2 = b1 + b4 * 0.5f;
        X1[q] = x1; Y1[q] = y1; X2[q] = x2; Y2[q] = y2;
        AR[q] = (x2 - x1) * (y2 - y1);
        sup[q] = 0;
    }
    __syncthreads();

    // greedy class-aware NMS scan, identical semantics to the reference scan
    for (int i = 0; i < TOPK; ++i) {
        const int keep_i = !sup[i];
        const int j = t;
        if (keep_i && j < TOPK && j > i && scls[j] == scls[i]) {
            const float xx1 = fmaxf(X1[i], X1[j]), yy1 = fmaxf(Y1[i], Y1[j]);
            const float xx2 = fminf(X2[i], X2[j]), yy2 = fminf(Y2[i], Y2[j]);
            const float inter = fmaxf(xx2 - xx1, 0.0f) * fmaxf(yy2 - yy1, 0.0f);
            const float iou = inter / (AR[i] + AR[j] - inter);
            if (iou > 0.5f) sup[j] = 1;  // NaN compares false, same as numpy
        }
        __syncthreads();
    }

    for (int q = t; q < TOPK; q += 128)
        k2[q] = sup[q] ? 1e9f : (float)scls[q] * 10.0f + (1.0f - ssc[q]);
    __syncthreads();

    float* oB = out;                       // 16*100*7
    float* oS = out + 11200;               // 16*100
    float* oC = out + 12800;               // 16*100 (classes as float values)
    float* oV = out + 14400;               // 16*100 (valid as 0/1 float)
    for (int q = t; q < TOPK; q += 128) {
        const float kq = k2[q];
        int r = 0;
        for (int j = 0; j < TOPK; ++j) {
            const float kj = k2[j];
            r += (kj < kq) || (kj == kq && j < q);  // stable argsort
        }
        const int keep = !sup[q];
        float* bo = oB + ((size_t)img * TOPK + r) * 7;
        #pragma unroll
        for (int d = 0; d < 7; ++d) bo[d] = keep ? bx[q][d] : 0.0f;
        oS[img * TOPK + r] = keep ? ssc[q] : 0.0f;
        oC[img * TOPK + r] = keep ? (float)scls[q] : 0.0f;
        oV[img * TOPK + r] = keep ? 1.0f : 0.0f;
    }
}

extern "C" void kernel_launch(void* const* d_in, const int* in_sizes, int n_in,
                              void* d_out, int out_size, void* d_ws, size_t ws_size,
                              hipStream_t stream) {
    const float* pred = (const float*)d_in[0];  // (16, 131072, 17) f32; anchors (d_in[1]) unused
    uint32_t* ws = (uint32_t*)d_ws;
    float* out = (float*)d_out;

    // zero hist + prefix + taken + cntA + cntB (u32 indices [0, 4160))
    hipMemsetAsync(ws, 0, 4160 * sizeof(uint32_t), stream);

    dim3 g(32, NIMG);
    k_keys_hist<<<g, 256, 0, stream>>>(pred, ws);
    k_refine<<<NIMG, 256, 0, stream>>>(ws);
    k_hist<<<g, 256, 0, stream>>>(ws, 16);
    k_refine<<<NIMG, 256, 0, stream>>>(ws);
    k_hist<<<g, 256, 0, stream>>>(ws, 8);
    k_refine<<<NIMG, 256, 0, stream>>>(ws);
    k_hist<<<g, 256, 0, stream>>>(ws, 0);
    k_refine<<<NIMG, 256, 0, stream>>>(ws);
    k_collect<<<g, 256, 0, stream>>>(ws);
    k_final<<<NIMG, 128, 0, stream>>>(pred, ws, out);
}